// Round 13
// baseline (315.019 us; speedup 1.0000x reference)
//
#include <hip/hip_runtime.h>

// ============================================================================
// Fused ViT attention block on MI355X (gfx950), all-bf16-MFMA pipeline.
//   B=4, N=2048, D=1024, H=16, Hd=64, M=B*N=8192
// Stages:
//   1) cvt x -> bf16; transpose W_qkv/W_proj -> [N][K] bf16
//   2) GEMM1: qkv = xb @ WqkvT (256x256 tile, 8 waves, BK=32, counted vmcnt)
//   3) v-transpose: vt[b,h,64,2048]
//   4) flash attention v7: 8-wave blocks (4 waves/SIMD), Qwave=32,
//      LDS-staged K/V (dbuf, XOR-swizzled), ones-trick denominator,
//      raw v_exp_f32, defer-max, XCD swizzle
//   5) GEMM2: out = ao @ WprojT + bias (fp32 out)
// ============================================================================

#define DEV __device__ __forceinline__

typedef __attribute__((ext_vector_type(8))) short bf16x8;
typedef __attribute__((ext_vector_type(4))) float f32x4;
typedef __attribute__((ext_vector_type(2))) __bf16 bf16x2v;

DEV unsigned short f2b(float f) {
  union { float f; unsigned u; } x; x.f = f;
  unsigned r = (x.u + 0x7FFFu + ((x.u >> 16) & 1u)) >> 16;
  return (unsigned short)r;
}

// packed f32 pair -> bf16 pair (compiler emits v_cvt_pk_bf16_f32)
DEV unsigned pkbf(float a, float b) {
  bf16x2v v; v[0] = (__bf16)a; v[1] = (__bf16)b;
  union { bf16x2v v; unsigned u; } x; x.v = v; return x.u;
}

// raw v_exp_f32 (args bounded by softmax max-subtraction; no fixup needed)
#if __has_builtin(__builtin_amdgcn_exp2f)
DEV float fexp2(float x) { return __builtin_amdgcn_exp2f(x); }
#else
DEV float fexp2(float x) { return __exp2f(x); }
#endif

DEV void gload16(const void* g, void* l) {
  __builtin_amdgcn_global_load_lds((const __attribute__((address_space(1))) void*)g,
                                   (__attribute__((address_space(3))) void*)l,
                                   16, 0, 0);
}

// ---------------------------------------------------------------------------
// fp32 -> bf16 elementwise (x)
__global__ void k_cvt(const float* __restrict__ in, unsigned short* __restrict__ out) {
  int i = (blockIdx.x * 256 + threadIdx.x) * 4;
  float4 v = *(const float4*)&in[i];
  *(uint2*)&out[i] = make_uint2(pkbf(v.x, v.y), pkbf(v.z, v.w));
}

// ---------------------------------------------------------------------------
// W[K][Nw] fp32 -> Wt[Nw][K] bf16 (LDS tile transpose)
__global__ void k_wt(const float* __restrict__ W, unsigned short* __restrict__ Wt,
                     int Nw, int K) {
  __shared__ float t[64][65];
  const int k0 = blockIdx.y * 64, n0 = blockIdx.x * 64;
  const int tx = threadIdx.x, ty = threadIdx.y;
#pragma unroll
  for (int i = 0; i < 16; ++i) {
    int r = i * 4 + ty;
    t[r][tx] = W[(size_t)(k0 + r) * Nw + n0 + tx];
  }
  __syncthreads();
#pragma unroll
  for (int i = 0; i < 16; ++i) {
    int r = i * 4 + ty;
    Wt[(size_t)(n0 + r) * K + k0 + tx] = f2b(t[tx][r]);
  }
}

// ---------------------------------------------------------------------------
// v slice of qkv -> vt[b,h,64,2048] (bf16 transpose via LDS)
__global__ void k_vt(const unsigned short* __restrict__ qkv, unsigned short* __restrict__ vt) {
  __shared__ unsigned short t[64][68];
  const int bh = blockIdx.y;
  const int b = bh >> 4, h = bh & 15;
  const int n0 = blockIdx.x * 64;
  const int tx = threadIdx.x, ty = threadIdx.y;
#pragma unroll
  for (int i = 0; i < 16; ++i) {
    int r = i * 4 + ty;
    t[r][tx] = qkv[(size_t)(b * 2048 + n0 + r) * 3072 + 2048 + h * 64 + tx];
  }
  __syncthreads();
#pragma unroll
  for (int i = 0; i < 16; ++i) {
    int d = i * 4 + ty;
    vt[(size_t)(bh * 64 + d) * 2048 + n0 + tx] = t[tx][d];
  }
}

// ---------------------------------------------------------------------------
// GEMM: C[M][N] = A[M][K] @ Bt[N][K]^T ; A,Bt bf16 row-major, k-contiguous.
// 256x256 tile, BK=32, 8 waves (2M x 4N), per-wave 128x64 output.
// MFMA:LDS-read balanced (per CU-K-tile: 1242 cyc MFMA vs 1130 cyc reads).
// Counted-vmcnt double buffer: STAGE(t+1) issued, then s_waitcnt vmcnt(4)
// (waits only tile t's 4 loads) + raw s_barrier -- t+1's loads stay in
// flight across the whole compute phase. LDS [256][32] (64B row stride)
// is naturally bank-conflict-free: bank = 4*chunk + 16*(row&1).
template <bool PROJ>
__global__ __launch_bounds__(512, 2) void gemm_bt(
    const unsigned short* __restrict__ A, const unsigned short* __restrict__ Bt,
    unsigned short* __restrict__ outB, float* __restrict__ outF,
    const float* __restrict__ bias, int M, int N, int K) {
  __shared__ unsigned short Al[2][256 * 32];
  __shared__ unsigned short Bl[2][256 * 32];
  const int tid = threadIdx.x;
  const int lane = tid & 63;
  const int wv = tid >> 6;             // 0..7
  const int m0 = blockIdx.y * 256;
  const int n0 = blockIdx.x * 256;
  const int wrow = (wv >> 2) * 128;    // 2 M-groups
  const int wcol = (wv & 3) * 64;      // 4 N-groups
  const int fr = lane & 15;
  const int fg = (lane >> 4) * 8;

  f32x4 acc[8][4];
#pragma unroll
  for (int i = 0; i < 8; ++i)
#pragma unroll
    for (int j = 0; j < 4; ++j) acc[i][j] = (f32x4){0.f, 0.f, 0.f, 0.f};

  // staging: wave wv covers rows [wv*32, wv*32+32) of A and Bt tiles.
  // lane -> (row = lane>>2, 16B chunk = lane&3) of a 16-row x 64B segment.
  const int srow = lane >> 2;
  const int scol = (lane & 3) * 8;
  const unsigned short* gA = A + (size_t)(m0 + wv * 32 + srow) * K + scol;
  const unsigned short* gB = Bt + (size_t)(n0 + wv * 32 + srow) * K + scol;

  auto STAGE = [&](int buf, int kt) {
    const size_t k0 = (size_t)kt << 5;
    gload16(gA + k0, &Al[buf][(wv * 32) * 32]);
    gload16(gA + k0 + (size_t)16 * K, &Al[buf][(wv * 32 + 16) * 32]);
    gload16(gB + k0, &Bl[buf][(wv * 32) * 32]);
    gload16(gB + k0 + (size_t)16 * K, &Bl[buf][(wv * 32 + 16) * 32]);
  };

  const int nk = K >> 5;  // 32
  STAGE(0, 0);
  for (int kt = 0; kt < nk; ++kt) {
    const int cur = kt & 1;
    if (kt + 1 < nk) {
      STAGE(cur ^ 1, kt + 1);
      // wait only tile t's 4 loads (oldest); t+1's 4 stay in flight
      asm volatile("s_waitcnt vmcnt(4)\n\ts_barrier" ::: "memory");
    } else {
      asm volatile("s_waitcnt vmcnt(0)\n\ts_barrier" ::: "memory");
    }
    const unsigned short* Ab = &Al[cur][0];
    const unsigned short* Bb = &Bl[cur][0];
    bf16x8 af[8], bfv[4];
#pragma unroll
    for (int i = 0; i < 8; ++i) af[i] = *(const bf16x8*)&Ab[(wrow + i * 16 + fr) * 32 + fg];
#pragma unroll
    for (int j = 0; j < 4; ++j) bfv[j] = *(const bf16x8*)&Bb[(wcol + j * 16 + fr) * 32 + fg];
    __builtin_amdgcn_s_setprio(1);
#pragma unroll
    for (int i = 0; i < 8; ++i)
#pragma unroll
      for (int j = 0; j < 4; ++j)
        acc[i][j] = __builtin_amdgcn_mfma_f32_16x16x32_bf16(af[i], bfv[j], acc[i][j], 0, 0, 0);
    __builtin_amdgcn_s_setprio(0);
    // all waves done reading buf[cur] before next iter's STAGE overwrites it
    asm volatile("s_barrier" ::: "memory");
  }

  const int rg = (lane >> 4) * 4;
#pragma unroll
  for (int i = 0; i < 8; ++i) {
#pragma unroll
    for (int j = 0; j < 4; ++j) {
      const int col = n0 + wcol + j * 16 + fr;
#pragma unroll
      for (int r = 0; r < 4; ++r) {
        const int row = m0 + wrow + i * 16 + rg + r;
        if (PROJ)
          outF[(size_t)row * N + col] = acc[i][j][r] + bias[col];
        else
          outB[(size_t)row * N + col] = f2b(acc[i][j][r]);
      }
    }
  }
}

// ---------------------------------------------------------------------------
// Flash attention v7 (unchanged from round 9 -- 95 us, 36.7% occupancy).
// Block = 8 waves (512 thr), one (b,h), 256 q-rows (32/wave). KVBLK=64.
__global__ __launch_bounds__(512, 4) void attn_k(
    const unsigned short* __restrict__ qkv, const unsigned short* __restrict__ vt,
    unsigned short* __restrict__ ao) {
  __shared__ unsigned short Kl[2][64 * 64];
  __shared__ unsigned short Vl[2][64 * 64];
  __shared__ unsigned short Pl[8][32 * 72];
  const int tid = threadIdx.x;
  const int lane = tid & 63;
  const int wv = tid >> 6;  // 0..7
  // XCD-aware swizzle (bijective: 512 % 8 == 0): XCD x gets bh in [8x, 8x+8)
  const int id = blockIdx.x;
  const int swz = (id & 7) * 64 + (id >> 3);
  const int bh = swz >> 3;
  const int b = bh >> 4, h = bh & 15;
  const int q0 = (swz & 7) * 256 + wv * 32;
  const int fr = lane & 15;
  const int hi = lane >> 4;
  const int g8 = hi * 8;
  const int g4 = hi * 4;
  const int fx = fr & 7;                   // read-side swizzle key
  const float CSC = 0.125f * 1.44269504f;  // head-scale * log2(e)
  const float THR = 4.0f;

  // staging geometry: lane covers (row = lane>>3, chunk = lane&7) of an
  // 8-row x 128B segment; source chunk pre-swizzled so LDS is chunk^(row&7).
  const int sr = lane >> 3;
  const int sc = ((lane & 7) ^ (sr & 7)) * 8;  // element offset of 16B chunk
  const unsigned short* gK =
      qkv + (size_t)(b * 2048 + wv * 8 + sr) * 3072 + 1024 + h * 64 + sc;
  const unsigned short* gV =
      vt + ((size_t)bh * 64 + wv * 8 + sr) * 2048 + sc;

  // Q fragments (B-operand of S^T): registers for the whole kernel
  bf16x8 bq[2][2];
#pragma unroll
  for (int qt = 0; qt < 2; ++qt)
#pragma unroll
    for (int ks = 0; ks < 2; ++ks)
      bq[qt][ks] = *(const bf16x8*)&qkv[(size_t)(b * 2048 + q0 + qt * 16 + fr) * 3072 +
                                        h * 64 + ks * 32 + g8];

  bf16x8 vones;
#pragma unroll
  for (int j = 0; j < 8; ++j) vones[j] = (short)0x3F80;  // bf16 1.0

  f32x4 acc[4][2];   // out^T: [d-tile][q-tile]
  f32x4 acc_l[2];    // ones-row sums (denominator); only [qt][0] is read
#pragma unroll
  for (int i = 0; i < 4; ++i)
#pragma unroll
    for (int j = 0; j < 2; ++j) acc[i][j] = (f32x4){0.f, 0.f, 0.f, 0.f};
  acc_l[0] = (f32x4){0.f, 0.f, 0.f, 0.f};
  acc_l[1] = (f32x4){0.f, 0.f, 0.f, 0.f};
  float m[2] = {-1e30f, -1e30f};

  // stage tile tt into buffer buf (each wave: 8 K-rows + 8 V-rows)
  auto STAGE = [&](int buf, int tt) {
    gload16(gK + (size_t)(tt * 64) * 3072, &Kl[buf][(wv * 8) * 64]);
    gload16(gV + tt * 64, &Vl[buf][(wv * 8) * 64]);
  };

  int cur = 0;
  STAGE(0, 0);
  __syncthreads();

  const f32x4 csc4 = (f32x4){CSC, CSC, CSC, CSC};

  for (int tt = 0; tt < 32; ++tt) {
    if (tt < 31) STAGE(cur ^ 1, tt + 1);
    const unsigned short* Kb = &Kl[cur][0];
    const unsigned short* Vb = &Vl[cur][0];

    // S^T = K · Q^T  (16 MFMA)
    f32x4 st[4][2];
    __builtin_amdgcn_s_setprio(1);
#pragma unroll
    for (int kk = 0; kk < 4; ++kk) {
      bf16x8 ak0 = *(const bf16x8*)&Kb[(kk * 16 + fr) * 64 + ((hi ^ fx) * 8)];
      bf16x8 ak1 = *(const bf16x8*)&Kb[(kk * 16 + fr) * 64 + (((4 + hi) ^ fx) * 8)];
#pragma unroll
      for (int qt = 0; qt < 2; ++qt) {
        f32x4 z = (f32x4){0.f, 0.f, 0.f, 0.f};
        z = __builtin_amdgcn_mfma_f32_16x16x32_bf16(ak0, bq[qt][0], z, 0, 0, 0);
        st[kk][qt] = __builtin_amdgcn_mfma_f32_16x16x32_bf16(ak1, bq[qt][1], z, 0, 0, 0);
      }
    }
    __builtin_amdgcn_s_setprio(0);

    // tile max per qt: packed vector max + 3-op horizontal
    f32x4 t0 = __builtin_elementwise_max(st[0][0], st[1][0]);
    t0 = __builtin_elementwise_max(t0, st[2][0]);
    t0 = __builtin_elementwise_max(t0, st[3][0]);
    f32x4 t1 = __builtin_elementwise_max(st[0][1], st[1][1]);
    t1 = __builtin_elementwise_max(t1, st[2][1]);
    t1 = __builtin_elementwise_max(t1, st[3][1]);
    const float c0 = fmaxf(fmaxf(t0[0], t0[1]), fmaxf(t0[2], t0[3])) * CSC;
    const float c1 = fmaxf(fmaxf(t1[0], t1[1]), fmaxf(t1[2], t1[3])) * CSC;

    // joint defer-max vote (THR in log2 units)
    if (!__all(c0 <= m[0] + THR && c1 <= m[1] + THR)) {
      const float cc[2] = {c0, c1};
#pragma unroll
      for (int qt = 0; qt < 2; ++qt) {
        float tm = cc[qt];
        tm = fmaxf(tm, __shfl_xor(tm, 16, 64));
        tm = fmaxf(tm, __shfl_xor(tm, 32, 64));
        const float mnew = fmaxf(m[qt], tm);
        const float corr = fexp2(m[qt] - mnew);
        m[qt] = mnew;
        acc_l[qt][0] *= corr;
#pragma unroll
        for (int dt = 0; dt < 4; ++dt) acc[dt][qt] *= corr;
      }
    }

    // P = exp2(st*CSC - m): packed fma + raw v_exp_f32, pack to bf16, stage
#pragma unroll
    for (int qt = 0; qt < 2; ++qt) {
      const float mq = m[qt];
      const f32x4 mq4 = (f32x4){-mq, -mq, -mq, -mq};
      const int prow = (qt * 16 + fr) * 72;
#pragma unroll
      for (int kk = 0; kk < 4; ++kk) {
        f32x4 e = __builtin_elementwise_fma(st[kk][qt], csc4, mq4);
        *(uint2*)&Pl[wv][prow + kk * 16 + g4] =
            make_uint2(pkbf(fexp2(e[0]), fexp2(e[1])), pkbf(fexp2(e[2]), fexp2(e[3])));
      }
    }

    // PV: out^T += V^T · P^T  (16 MFMA) ; denominator += ones · P^T (4 MFMA)
#pragma unroll
    for (int ks2 = 0; ks2 < 2; ++ks2) {
      bf16x8 bp0 = *(const bf16x8*)&Pl[wv][(0 * 16 + fr) * 72 + ks2 * 32 + g8];
      bf16x8 bp1 = *(const bf16x8*)&Pl[wv][(1 * 16 + fr) * 72 + ks2 * 32 + g8];
      __builtin_amdgcn_s_setprio(1);
#pragma unroll
      for (int dt = 0; dt < 4; ++dt) {
        bf16x8 av = *(const bf16x8*)&Vb[(dt * 16 + fr) * 64 + (((ks2 * 4 + hi) ^ fx) * 8)];
        acc[dt][0] = __builtin_amdgcn_mfma_f32_16x16x32_bf16(av, bp0, acc[dt][0], 0, 0, 0);
        acc[dt][1] = __builtin_amdgcn_mfma_f32_16x16x32_bf16(av, bp1, acc[dt][1], 0, 0, 0);
      }
      acc_l[0] = __builtin_amdgcn_mfma_f32_16x16x32_bf16(vones, bp0, acc_l[0], 0, 0, 0);
      acc_l[1] = __builtin_amdgcn_mfma_f32_16x16x32_bf16(vones, bp1, acc_l[1], 0, 0, 0);
      __builtin_amdgcn_s_setprio(0);
    }

    __syncthreads();
    cur ^= 1;
  }

  // normalize + store (bf16, [b*2048+n][h*64+d]); acc_l[qt][0] is the full
  // denominator for q = q0 + qt*16 + fr
#pragma unroll
  for (int qt = 0; qt < 2; ++qt) {
    const float inv = 1.0f / acc_l[qt][0];
#pragma unroll
    for (int dt = 0; dt < 4; ++dt) {
      uint2 o = make_uint2(pkbf(acc[dt][qt][0] * inv, acc[dt][qt][1] * inv),
                           pkbf(acc[dt][qt][2] * inv, acc[dt][qt][3] * inv));
      *(uint2*)&ao[(size_t)(b * 2048 + q0 + qt * 16 + fr) * 1024 + h * 64 + dt * 16 + g4] = o;
    }
  }
}

// ---------------------------------------------------------------------------
extern "C" void kernel_launch(void* const* d_in, const int* in_sizes, int n_in,
                              void* d_out, int out_size, void* d_ws, size_t ws_size,
                              hipStream_t stream) {
  const float* x     = (const float*)d_in[0];
  const float* wqkv  = (const float*)d_in[1];
  const float* wproj = (const float*)d_in[2];
  const float* bproj = (const float*)d_in[3];
  float* out = (float*)d_out;
  char* ws = (char*)d_ws;

  // workspace layout (bytes)
  unsigned short* xb     = (unsigned short*)(ws + 0);          // 16.78 MB
  unsigned short* wqkvT  = (unsigned short*)(ws + 16777216);   //  6.29 MB
  unsigned short* wprojT = (unsigned short*)(ws + 23068672);   //  2.10 MB
  unsigned short* qkv    = (unsigned short*)(ws + 25165824);   // 50.33 MB
  unsigned short* vt     = (unsigned short*)(ws + 75497472);   // 16.78 MB
  unsigned short* ao     = (unsigned short*)(ws + 92274688);   // 16.78 MB

  k_cvt<<<8192, 256, 0, stream>>>(x, xb);
  k_wt<<<dim3(48, 16), dim3(64, 4), 0, stream>>>(wqkv, wqkvT, 3072, 1024);
  k_wt<<<dim3(16, 16), dim3(64, 4), 0, stream>>>(wproj, wprojT, 1024, 1024);
  gemm_bt<false><<<dim3(12, 32), 512, 0, stream>>>(xb, wqkvT, qkv, nullptr, nullptr,
                                                   8192, 3072, 1024);
  k_vt<<<dim3(32, 64), dim3(64, 4), 0, stream>>>(qkv, vt);
  attn_k<<<512, 512, 0, stream>>>(qkv, vt, ao);
  gemm_bt<true><<<dim3(4, 32), 512, 0, stream>>>(ao, wprojT, nullptr, out, bproj,
                                                 8192, 1024, 1024);
}